// Round 2
// baseline (394.643 us; speedup 1.0000x reference)
//
#include <hip/hip_runtime.h>
#include <hip/hip_bf16.h>

#define N 8192
#define IN_F 128
#define OUT_F 64
#define LRELU_ALPHA 0.2f
#define PAD 520  // shorts per p-row (512 + 8; keeps 16B alignment, breaks pow2)

typedef __attribute__((ext_vector_type(8))) short short8;
typedef __attribute__((ext_vector_type(4))) float float4v;
typedef __attribute__((ext_vector_type(4))) unsigned short ushortx4;

__device__ __forceinline__ unsigned short bf16_bits(float x) {
  unsigned u = __builtin_bit_cast(unsigned, x);
  u += 0x7fffu + ((u >> 16) & 1u);  // round-to-nearest-even
  return (unsigned short)(u >> 16);
}

// prep: Wh = h@W (fp32), s1 = Wh@a1, s2 = Wh@a2, whT bf16 [64][8192]
__global__ __launch_bounds__(256) void prep_kernel(
    const float* __restrict__ h, const float* __restrict__ W,
    const float* __restrict__ a, float* __restrict__ s1,
    float* __restrict__ s2, unsigned short* __restrict__ whT) {
  const int tid = threadIdx.x;
  const int row = blockIdx.x * 4 + (tid >> 6);
  const int k = tid & 63;
  const float4* hr4 = (const float4*)(h + row * IN_F);
  float acc = 0.f;
#pragma unroll
  for (int c4 = 0; c4 < IN_F / 4; ++c4) {
    const float4 hv = hr4[c4];
    const int cb = c4 * 4;
    acc = fmaf(hv.x, W[(cb + 0) * OUT_F + k], acc);
    acc = fmaf(hv.y, W[(cb + 1) * OUT_F + k], acc);
    acc = fmaf(hv.z, W[(cb + 2) * OUT_F + k], acc);
    acc = fmaf(hv.w, W[(cb + 3) * OUT_F + k], acc);
  }
  whT[(long)k * N + row] = bf16_bits(acc);
  float p1 = acc * a[k];
  float p2 = acc * a[OUT_F + k];
#pragma unroll
  for (int off = 32; off > 0; off >>= 1) {
    p1 += __shfl_xor(p1, off);
    p2 += __shfl_xor(p2, off);
  }
  if (k == 0) { s1[row] = p1; s2[row] = p2; }
}

// repack whT [64][8192] -> B-fragment order: whF[(c32*256 + tt*64 + lane)*8]
// lane=(quad,r16): holds Wh[node=c32*32+quad*8+j][dim=tt*16+r16], j=0..7.
__global__ __launch_bounds__(256) void repack_kernel(
    const unsigned short* __restrict__ whT, unsigned short* __restrict__ whF) {
  const int f = blockIdx.x * 256 + threadIdx.x;  // 0..65535 fragments
  const int lane = f & 63, tt = (f >> 6) & 3, c = f >> 8;
  const int r16 = lane & 15, quad = lane >> 4;
  const short8 v = *(const short8*)(whT + (long)(tt * 16 + r16) * N + c * 32 + quad * 8);
  *(short8*)(whF + (long)f * 8) = v;
}

__device__ __forceinline__ void p_write(unsigned short* pr, int c, int4 av,
                                        float4 s2v, float s1w) {
  float e0 = s1w + s2v.x; e0 = fmaxf(e0, LRELU_ALPHA * e0);
  float e1 = s1w + s2v.y; e1 = fmaxf(e1, LRELU_ALPHA * e1);
  float e2 = s1w + s2v.z; e2 = fmaxf(e2, LRELU_ALPHA * e2);
  float e3 = s1w + s2v.w; e3 = fmaxf(e3, LRELU_ALPHA * e3);
  const float p0 = av.x > 0 ? __expf(e0) : 0.f;
  const float p1 = av.y > 0 ? __expf(e1) : 0.f;
  const float p2 = av.z > 0 ? __expf(e2) : 0.f;
  const float p3 = av.w > 0 ? __expf(e3) : 0.f;
  ushortx4 pk = {bf16_bits(p0), bf16_bits(p1), bf16_bits(p2), bf16_bits(p3)};
  *(ushortx4*)(pr + c) = pk;
}

// Fused GAT v2: 512 blocks x 512 thr (8 waves), 16 rows/block.
// Wave w owns adj rows {2w, 2w+1} (contiguous 1KB bursts) and MFMA col-chunks
// {w, w+8}. adj prefetched TWO iters ahead (2 reg sets, statically indexed via
// full unroll); s2 one iter ahead. 512-thr blocks => 2 independent blocks/CU
// at <=128 VGPR: cross-block latency overlap that one 1024-thr block lacks.
__global__ __launch_bounds__(512, 4) void gat_kernel(
    const int* __restrict__ adj, const float* __restrict__ s1,
    const float* __restrict__ s2, const unsigned short* __restrict__ whF,
    float* __restrict__ out) {
  __shared__ __align__(16) unsigned short pbuf[2][16][PAD];  // 33280 B
  const int tid = threadIdx.x;
  const int w = tid >> 6, L = tid & 63;
  const int r16 = L & 15, quad = L >> 4;
  const int row0 = blockIdx.x * 16;
  const int rA = 2 * w, rB = 2 * w + 1;
  const long arowA = (long)(row0 + rA) * N;
  const long arowB = (long)(row0 + rB) * N;
  const float s1A = s1[row0 + rA];
  const float s1B = s1[row0 + rB];
  const int c = L * 4;

  float4v acc0 = {0.f, 0.f, 0.f, 0.f};
  float4v acc1 = {0.f, 0.f, 0.f, 0.f};
  float4v acc2 = {0.f, 0.f, 0.f, 0.f};
  float4v acc3 = {0.f, 0.f, 0.f, 0.f};
  float4v accD = {0.f, 0.f, 0.f, 0.f};
  const short ONE = (short)0x3F80;  // bf16 1.0
  const short8 ones = {ONE, ONE, ONE, ONE, ONE, ONE, ONE, ONE};

  // 2-deep adj prefetch regs: set s holds segment (it+1) where s == it&1
  int4 pA0[2], pA1[2], pB0[2], pB1[2];
  float4 ps0, ps1;  // s2, 1-deep (L2-hot)

  // prologue: seg0 p + issue prefetches for seg1/seg2
  {
    const int4 a0 = *(const int4*)(adj + arowA + c);
    const int4 a1 = *(const int4*)(adj + arowA + 256 + c);
    const int4 b0 = *(const int4*)(adj + arowB + c);
    const int4 b1 = *(const int4*)(adj + arowB + 256 + c);
    const float4 sv0 = *(const float4*)(s2 + c);
    const float4 sv1 = *(const float4*)(s2 + 256 + c);
    pA0[0] = *(const int4*)(adj + arowA + 512 + c);
    pA1[0] = *(const int4*)(adj + arowA + 512 + 256 + c);
    pB0[0] = *(const int4*)(adj + arowB + 512 + c);
    pB1[0] = *(const int4*)(adj + arowB + 512 + 256 + c);
    pA0[1] = *(const int4*)(adj + arowA + 1024 + c);
    pA1[1] = *(const int4*)(adj + arowA + 1024 + 256 + c);
    pB0[1] = *(const int4*)(adj + arowB + 1024 + c);
    pB1[1] = *(const int4*)(adj + arowB + 1024 + 256 + c);
    ps0 = *(const float4*)(s2 + 512 + c);
    ps1 = *(const float4*)(s2 + 512 + 256 + c);
    p_write(pbuf[0][rA], c, a0, sv0, s1A);
    p_write(pbuf[0][rA], 256 + c, a1, sv1, s1A);
    p_write(pbuf[0][rB], c, b0, sv0, s1B);
    p_write(pbuf[0][rB], 256 + c, b1, sv1, s1B);
  }
  __syncthreads();

#pragma unroll
  for (int it = 0; it < 16; ++it) {
    const int b = it & 1;
    const int s = it & 1;
    // MFMA phase: this wave's two 32-col chunks (accumulate over cols)
#pragma unroll
    for (int half = 0; half < 2; ++half) {
      const int cc = w + half * 8;
      const short8 afrag = *(const short8*)(&pbuf[b][r16][cc * 32 + quad * 8]);
      const unsigned short* bp = whF + ((long)(it * 16 + cc) * 256 + L) * 8;
      const short8 b0 = *(const short8*)(bp);
      const short8 b1 = *(const short8*)(bp + 512);
      const short8 b2 = *(const short8*)(bp + 1024);
      const short8 b3 = *(const short8*)(bp + 1536);
      acc0 = __builtin_amdgcn_mfma_f32_16x16x32_bf16(afrag, b0, acc0, 0, 0, 0);
      acc1 = __builtin_amdgcn_mfma_f32_16x16x32_bf16(afrag, b1, acc1, 0, 0, 0);
      acc2 = __builtin_amdgcn_mfma_f32_16x16x32_bf16(afrag, b2, acc2, 0, 0, 0);
      acc3 = __builtin_amdgcn_mfma_f32_16x16x32_bf16(afrag, b3, acc3, 0, 0, 0);
      accD = __builtin_amdgcn_mfma_f32_16x16x32_bf16(afrag, ones, accD, 0, 0, 0);
    }
    if (it < 15) {  // stage p(it+1) from regs loaded 2 iters ago
      unsigned short* prA = pbuf[b ^ 1][rA];
      unsigned short* prB = pbuf[b ^ 1][rB];
      p_write(prA, c, pA0[s], ps0, s1A);
      p_write(prA, 256 + c, pA1[s], ps1, s1A);
      p_write(prB, c, pB0[s], ps0, s1B);
      p_write(prB, 256 + c, pB1[s], ps1, s1B);
      if (it < 13) {  // refill consumed set with segment it+3
        const long base = (long)(it + 3) * 512 + c;
        pA0[s] = *(const int4*)(adj + arowA + base);
        pA1[s] = *(const int4*)(adj + arowA + base + 256);
        pB0[s] = *(const int4*)(adj + arowB + base);
        pB1[s] = *(const int4*)(adj + arowB + base + 256);
      }
      if (it < 14) {  // s2 for segment it+2
        ps0 = *(const float4*)(s2 + (it + 2) * 512 + c);
        ps1 = *(const float4*)(s2 + (it + 2) * 512 + 256 + c);
      }
    }
    __syncthreads();
  }

  // merge 8 wave-partials in LDS (aliases pbuf; 4 slots x 1040 floats)
  float* M = (float*)pbuf;
  if (w >= 4) {
    float* S = M + (w - 4) * 1040;
#pragma unroll
    for (int reg = 0; reg < 4; ++reg) {
      const int r = quad * 4 + reg;  // C-layout: row=quad*4+reg, col=r16
      S[r * 64 + 0 * 16 + r16] = acc0[reg];
      S[r * 64 + 1 * 16 + r16] = acc1[reg];
      S[r * 64 + 2 * 16 + r16] = acc2[reg];
      S[r * 64 + 3 * 16 + r16] = acc3[reg];
      if (r16 == 0) S[1024 + r] = accD[reg];
    }
  }
  __syncthreads();
  if (w < 4) {
    float* S = M + w * 1040;
#pragma unroll
    for (int reg = 0; reg < 4; ++reg) {
      const int r = quad * 4 + reg;
      S[r * 64 + 0 * 16 + r16] += acc0[reg];
      S[r * 64 + 1 * 16 + r16] += acc1[reg];
      S[r * 64 + 2 * 16 + r16] += acc2[reg];
      S[r * 64 + 3 * 16 + r16] += acc3[reg];
      if (r16 == 0) S[1024 + r] += accD[reg];
    }
  }
  __syncthreads();
#pragma unroll
  for (int part = 0; part < 2; ++part) {
    const int e = part * 512 + tid;
    const int r = e >> 6, k = e & 63;
    float Sv = 0.f, Lv = 0.f;
#pragma unroll
    for (int sl = 0; sl < 4; ++sl) {
      Sv += M[sl * 1040 + r * 64 + k];
      Lv += M[sl * 1040 + 1024 + r];
    }
    const float v = Sv / Lv;
    out[(long)(row0 + r) * OUT_F + k] = v > 0.f ? v : expm1f(v);
  }
}

extern "C" void kernel_launch(void* const* d_in, const int* in_sizes, int n_in,
                              void* d_out, int out_size, void* d_ws, size_t ws_size,
                              hipStream_t stream) {
  const float* h = (const float*)d_in[0];
  const int* adj = (const int*)d_in[1];
  const float* W = (const float*)d_in[2];
  const float* a = (const float*)d_in[3];
  float* out = (float*)d_out;

  // ws: s1[8192] | s2[8192] | whT[64*8192] bf16 | whF[64*8192] bf16 (~2.1MB)
  float* s1 = (float*)d_ws;
  float* s2 = s1 + N;
  unsigned short* whT = (unsigned short*)(s2 + N);
  unsigned short* whF = whT + (long)OUT_F * N;

  prep_kernel<<<N / 4, 256, 0, stream>>>(h, W, a, s1, s2, whT);
  repack_kernel<<<N * OUT_F / 8 / 256, 256, 0, stream>>>(whT, whF);
  gat_kernel<<<N / 16, 512, 0, stream>>>(adj, s1, s2, whF, out);
}

// Round 3
// 387.811 us; speedup vs baseline: 1.0176x; 1.0176x over previous
//
#include <hip/hip_runtime.h>
#include <hip/hip_bf16.h>

#define N 8192
#define IN_F 128
#define OUT_F 64
#define LRELU_ALPHA 0.2f
#define PAD 520        // shorts per p-row (512 + 8; keeps 16B alignment, breaks pow2)
#define HS_STRIDE 129  // floats per staged h-row (+1: quads hit distinct banks)

typedef __attribute__((ext_vector_type(8))) short short8;
typedef __attribute__((ext_vector_type(4))) float float4v;
typedef __attribute__((ext_vector_type(4))) unsigned short ushortx4;

__device__ __forceinline__ unsigned short bf16_bits(float x) {
  unsigned u = __builtin_bit_cast(unsigned, x);
  u += 0x7fffu + ((u >> 16) & 1u);  // round-to-nearest-even
  return (unsigned short)(u >> 16);
}

// Fused prep: computes Wh = h@W and writes whF in MFMA B-fragment order
// DIRECTLY (no whT intermediate, no repack pass), plus s1 = Wh@a1, s2 = Wh@a2.
// Block = one c32 chunk (32 nodes, all 64 dims); thread (w,L) computes
// Wh[node = c32*32 + quad*8 + j][dim = w*16 + r16] for j=0..7 — exactly one
// B-fragment (16B contiguous store at whF[(c32*256 + w*64 + L)*8]).
__global__ __launch_bounds__(256) void prep_kernel(
    const float* __restrict__ h, const float* __restrict__ W,
    const float* __restrict__ a, float* __restrict__ s1,
    float* __restrict__ s2, unsigned short* __restrict__ whF) {
  __shared__ float hs[32 * HS_STRIDE];  // 16.5 KB
  __shared__ float sred[4][4][8][2];    // [wave][quad][j][p1|p2]
  const int tid = threadIdx.x;
  const int c32 = blockIdx.x;  // 0..255
  const int w = tid >> 6, L = tid & 63;
  const int r16 = L & 15, quad = L >> 4;
  const int d = w * 16 + r16;

  // stage h rows [c32*32, c32*32+32) into LDS
  {
    const int row = tid >> 3;          // 0..31
    const int col0 = (tid & 7) * 16;   // 0..112
    const float4* src = (const float4*)(h + (long)(c32 * 32 + row) * IN_F + col0);
#pragma unroll
    for (int i = 0; i < 4; ++i) {
      const float4 v = src[i];
      float* dst = hs + row * HS_STRIDE + col0 + i * 4;
      dst[0] = v.x; dst[1] = v.y; dst[2] = v.z; dst[3] = v.w;
    }
  }
  __syncthreads();

  float acc[8] = {0.f, 0.f, 0.f, 0.f, 0.f, 0.f, 0.f, 0.f};
  const float* hb = hs + (quad * 8) * HS_STRIDE;
#pragma unroll 4
  for (int cidx = 0; cidx < IN_F; ++cidx) {
    const float wv = W[cidx * OUT_F + d];
#pragma unroll
    for (int j = 0; j < 8; ++j)
      acc[j] = fmaf(hb[j * HS_STRIDE + cidx], wv, acc[j]);
  }

  // direct whF fragment store (16B contiguous per thread)
  {
    ushortx4 lo = {bf16_bits(acc[0]), bf16_bits(acc[1]),
                   bf16_bits(acc[2]), bf16_bits(acc[3])};
    ushortx4 hi = {bf16_bits(acc[4]), bf16_bits(acc[5]),
                   bf16_bits(acc[6]), bf16_bits(acc[7])};
    unsigned short* dst = whF + ((long)c32 * 256 + w * 64 + L) * 8;
    *(ushortx4*)(dst) = lo;
    *(ushortx4*)(dst + 4) = hi;
  }

  // s1/s2: reduce acc[j]*a1[d], acc[j]*a2[d] over the 64 dims.
  const float a1d = a[d], a2d = a[OUT_F + d];
  float p1[8], p2[8];
#pragma unroll
  for (int j = 0; j < 8; ++j) { p1[j] = acc[j] * a1d; p2[j] = acc[j] * a2d; }
#pragma unroll
  for (int off = 1; off < 16; off <<= 1) {  // reduce across r16 within quad
#pragma unroll
    for (int j = 0; j < 8; ++j) {
      p1[j] += __shfl_xor(p1[j], off);
      p2[j] += __shfl_xor(p2[j], off);
    }
  }
  if (r16 == 0) {
#pragma unroll
    for (int j = 0; j < 8; ++j) {
      sred[w][quad][j][0] = p1[j];
      sred[w][quad][j][1] = p2[j];
    }
  }
  __syncthreads();
  if (tid < 32) {
    const int q = tid >> 3, j = tid & 7;
    float v1 = 0.f, v2 = 0.f;
#pragma unroll
    for (int ww = 0; ww < 4; ++ww) {
      v1 += sred[ww][q][j][0];
      v2 += sred[ww][q][j][1];
    }
    const int row = c32 * 32 + q * 8 + j;
    s1[row] = v1;
    s2[row] = v2;
  }
}

__device__ __forceinline__ void p_write(unsigned short* pr, int c, int4 av,
                                        float4 s2v, float s1w) {
  float e0 = s1w + s2v.x; e0 = fmaxf(e0, LRELU_ALPHA * e0);
  float e1 = s1w + s2v.y; e1 = fmaxf(e1, LRELU_ALPHA * e1);
  float e2 = s1w + s2v.z; e2 = fmaxf(e2, LRELU_ALPHA * e2);
  float e3 = s1w + s2v.w; e3 = fmaxf(e3, LRELU_ALPHA * e3);
  const float p0 = av.x > 0 ? __expf(e0) : 0.f;
  const float p1 = av.y > 0 ? __expf(e1) : 0.f;
  const float p2 = av.z > 0 ? __expf(e2) : 0.f;
  const float p3 = av.w > 0 ? __expf(e3) : 0.f;
  ushortx4 pk = {bf16_bits(p0), bf16_bits(p1), bf16_bits(p2), bf16_bits(p3)};
  *(ushortx4*)(pr + c) = pk;
}

// Fused GAT v2: 512 blocks x 512 thr (8 waves), 16 rows/block.
// Wave w owns adj rows {2w, 2w+1} (contiguous 1KB bursts) and MFMA col-chunks
// {w, w+8}. adj prefetched TWO iters ahead (2 reg sets, statically indexed via
// full unroll); s2 one iter ahead. 512-thr blocks => 2 independent blocks/CU
// at <=128 VGPR: cross-block latency overlap that one 1024-thr block lacks.
__global__ __launch_bounds__(512, 4) void gat_kernel(
    const int* __restrict__ adj, const float* __restrict__ s1,
    const float* __restrict__ s2, const unsigned short* __restrict__ whF,
    float* __restrict__ out) {
  __shared__ __align__(16) unsigned short pbuf[2][16][PAD];  // 33280 B
  const int tid = threadIdx.x;
  const int w = tid >> 6, L = tid & 63;
  const int r16 = L & 15, quad = L >> 4;
  const int row0 = blockIdx.x * 16;
  const int rA = 2 * w, rB = 2 * w + 1;
  const long arowA = (long)(row0 + rA) * N;
  const long arowB = (long)(row0 + rB) * N;
  const float s1A = s1[row0 + rA];
  const float s1B = s1[row0 + rB];
  const int c = L * 4;

  float4v acc0 = {0.f, 0.f, 0.f, 0.f};
  float4v acc1 = {0.f, 0.f, 0.f, 0.f};
  float4v acc2 = {0.f, 0.f, 0.f, 0.f};
  float4v acc3 = {0.f, 0.f, 0.f, 0.f};
  float4v accD = {0.f, 0.f, 0.f, 0.f};
  const short ONE = (short)0x3F80;  // bf16 1.0
  const short8 ones = {ONE, ONE, ONE, ONE, ONE, ONE, ONE, ONE};

  // 2-deep adj prefetch regs: set s holds segment (it+1) where s == it&1
  int4 pA0[2], pA1[2], pB0[2], pB1[2];
  float4 ps0, ps1;  // s2, 1-deep (L2-hot)

  // prologue: seg0 p + issue prefetches for seg1/seg2
  {
    const int4 a0 = *(const int4*)(adj + arowA + c);
    const int4 a1 = *(const int4*)(adj + arowA + 256 + c);
    const int4 b0 = *(const int4*)(adj + arowB + c);
    const int4 b1 = *(const int4*)(adj + arowB + 256 + c);
    const float4 sv0 = *(const float4*)(s2 + c);
    const float4 sv1 = *(const float4*)(s2 + 256 + c);
    pA0[0] = *(const int4*)(adj + arowA + 512 + c);
    pA1[0] = *(const int4*)(adj + arowA + 512 + 256 + c);
    pB0[0] = *(const int4*)(adj + arowB + 512 + c);
    pB1[0] = *(const int4*)(adj + arowB + 512 + 256 + c);
    pA0[1] = *(const int4*)(adj + arowA + 1024 + c);
    pA1[1] = *(const int4*)(adj + arowA + 1024 + 256 + c);
    pB0[1] = *(const int4*)(adj + arowB + 1024 + c);
    pB1[1] = *(const int4*)(adj + arowB + 1024 + 256 + c);
    ps0 = *(const float4*)(s2 + 512 + c);
    ps1 = *(const float4*)(s2 + 512 + 256 + c);
    p_write(pbuf[0][rA], c, a0, sv0, s1A);
    p_write(pbuf[0][rA], 256 + c, a1, sv1, s1A);
    p_write(pbuf[0][rB], c, b0, sv0, s1B);
    p_write(pbuf[0][rB], 256 + c, b1, sv1, s1B);
  }
  __syncthreads();

#pragma unroll
  for (int it = 0; it < 16; ++it) {
    const int b = it & 1;
    const int s = it & 1;
    // MFMA phase: this wave's two 32-col chunks (accumulate over cols)
#pragma unroll
    for (int half = 0; half < 2; ++half) {
      const int cc = w + half * 8;
      const short8 afrag = *(const short8*)(&pbuf[b][r16][cc * 32 + quad * 8]);
      const unsigned short* bp = whF + ((long)(it * 16 + cc) * 256 + L) * 8;
      const short8 b0 = *(const short8*)(bp);
      const short8 b1 = *(const short8*)(bp + 512);
      const short8 b2 = *(const short8*)(bp + 1024);
      const short8 b3 = *(const short8*)(bp + 1536);
      acc0 = __builtin_amdgcn_mfma_f32_16x16x32_bf16(afrag, b0, acc0, 0, 0, 0);
      acc1 = __builtin_amdgcn_mfma_f32_16x16x32_bf16(afrag, b1, acc1, 0, 0, 0);
      acc2 = __builtin_amdgcn_mfma_f32_16x16x32_bf16(afrag, b2, acc2, 0, 0, 0);
      acc3 = __builtin_amdgcn_mfma_f32_16x16x32_bf16(afrag, b3, acc3, 0, 0, 0);
      accD = __builtin_amdgcn_mfma_f32_16x16x32_bf16(afrag, ones, accD, 0, 0, 0);
    }
    if (it < 15) {  // stage p(it+1) from regs loaded 2 iters ago
      unsigned short* prA = pbuf[b ^ 1][rA];
      unsigned short* prB = pbuf[b ^ 1][rB];
      p_write(prA, c, pA0[s], ps0, s1A);
      p_write(prA, 256 + c, pA1[s], ps1, s1A);
      p_write(prB, c, pB0[s], ps0, s1B);
      p_write(prB, 256 + c, pB1[s], ps1, s1B);
      if (it < 13) {  // refill consumed set with segment it+3
        const long base = (long)(it + 3) * 512 + c;
        pA0[s] = *(const int4*)(adj + arowA + base);
        pA1[s] = *(const int4*)(adj + arowA + base + 256);
        pB0[s] = *(const int4*)(adj + arowB + base);
        pB1[s] = *(const int4*)(adj + arowB + base + 256);
      }
      if (it < 14) {  // s2 for segment it+2
        ps0 = *(const float4*)(s2 + (it + 2) * 512 + c);
        ps1 = *(const float4*)(s2 + (it + 2) * 512 + 256 + c);
      }
    }
    __syncthreads();
  }

  // merge 8 wave-partials in LDS (aliases pbuf; 4 slots x 1040 floats)
  float* M = (float*)pbuf;
  if (w >= 4) {
    float* S = M + (w - 4) * 1040;
#pragma unroll
    for (int reg = 0; reg < 4; ++reg) {
      const int r = quad * 4 + reg;  // C-layout: row=quad*4+reg, col=r16
      S[r * 64 + 0 * 16 + r16] = acc0[reg];
      S[r * 64 + 1 * 16 + r16] = acc1[reg];
      S[r * 64 + 2 * 16 + r16] = acc2[reg];
      S[r * 64 + 3 * 16 + r16] = acc3[reg];
      if (r16 == 0) S[1024 + r] = accD[reg];
    }
  }
  __syncthreads();
  if (w < 4) {
    float* S = M + w * 1040;
#pragma unroll
    for (int reg = 0; reg < 4; ++reg) {
      const int r = quad * 4 + reg;
      S[r * 64 + 0 * 16 + r16] += acc0[reg];
      S[r * 64 + 1 * 16 + r16] += acc1[reg];
      S[r * 64 + 2 * 16 + r16] += acc2[reg];
      S[r * 64 + 3 * 16 + r16] += acc3[reg];
      if (r16 == 0) S[1024 + r] += accD[reg];
    }
  }
  __syncthreads();
#pragma unroll
  for (int part = 0; part < 2; ++part) {
    const int e = part * 512 + tid;
    const int r = e >> 6, k = e & 63;
    float Sv = 0.f, Lv = 0.f;
#pragma unroll
    for (int sl = 0; sl < 4; ++sl) {
      Sv += M[sl * 1040 + r * 64 + k];
      Lv += M[sl * 1040 + 1024 + r];
    }
    const float v = Sv / Lv;
    out[(long)(row0 + r) * OUT_F + k] = v > 0.f ? v : expm1f(v);
  }
}

extern "C" void kernel_launch(void* const* d_in, const int* in_sizes, int n_in,
                              void* d_out, int out_size, void* d_ws, size_t ws_size,
                              hipStream_t stream) {
  const float* h = (const float*)d_in[0];
  const int* adj = (const int*)d_in[1];
  const float* W = (const float*)d_in[2];
  const float* a = (const float*)d_in[3];
  float* out = (float*)d_out;

  // ws: s1[8192] | s2[8192] | whF[64*8192] bf16 (~1.1MB)
  float* s1 = (float*)d_ws;
  float* s2 = s1 + N;
  unsigned short* whF = (unsigned short*)(s2 + N);

  prep_kernel<<<N / 32, 256, 0, stream>>>(h, W, a, s1, s2, whF);
  gat_kernel<<<N / 16, 512, 0, stream>>>(adj, s1, s2, whF, out);
}

// Round 4
// 383.678 us; speedup vs baseline: 1.0286x; 1.0108x over previous
//
#include <hip/hip_runtime.h>
#include <hip/hip_bf16.h>

#define N 8192
#define IN_F 128
#define OUT_F 64
#define LRELU_ALPHA 0.2f
#define PAD 520      // shorts per p-row (512 + 8; keeps 16B alignment, breaks pow2)
#define HSTRIDE 132  // floats per staged h-row (16B-aligned, breaks pow2)
#define WTSTRIDE 132 // floats per staged W^T row

typedef __attribute__((ext_vector_type(8))) short short8;
typedef __attribute__((ext_vector_type(4))) float float4v;
typedef __attribute__((ext_vector_type(4))) unsigned short ushortx4;

__device__ __forceinline__ unsigned short bf16_bits(float x) {
  unsigned u = __builtin_bit_cast(unsigned, x);
  u += 0x7fffu + ((u >> 16) & 1u);  // round-to-nearest-even
  return (unsigned short)(u >> 16);
}

// Fused prep v3: Wh = h@W with BOTH operands staged in LDS (h rows + W^T),
// all inner-loop reads ds_read_b128. Thread (w,L): computes
// Wh[node = c32*32 + quad*8 + j][dim = w*16 + r16], j=0..7 — one B-fragment
// (16B contiguous store). Also s1 = Wh@a1, s2 = Wh@a2 via shfl+LDS reduce.
__global__ __launch_bounds__(256) void prep_kernel(
    const float* __restrict__ h, const float* __restrict__ W,
    const float* __restrict__ a, float* __restrict__ s1,
    float* __restrict__ s2, unsigned short* __restrict__ whF) {
  __shared__ float hs[32 * HSTRIDE];   // 16.9 KB
  __shared__ float wt[64 * WTSTRIDE];  // 33.8 KB
  __shared__ float sred[4][4][8][2];   // [wave][quad][j][p1|p2]
  const int tid = threadIdx.x;
  const int c32 = blockIdx.x;  // 0..255
  const int w = tid >> 6, L = tid & 63;
  const int r16 = L & 15, quad = L >> 4;
  const int d = w * 16 + r16;

  // stage h rows [c32*32, c32*32+32) into LDS (float4 stores, 16B aligned)
  {
    const int row = tid >> 3;         // 0..31
    const int col0 = (tid & 7) * 16;  // 0..112
    const float4* src = (const float4*)(h + (long)(c32 * 32 + row) * IN_F + col0);
#pragma unroll
    for (int i = 0; i < 4; ++i)
      *(float4*)(hs + row * HSTRIDE + col0 + i * 4) = src[i];
  }
  // stage W transposed: wt[d][c] = W[c][d] (coalesced global reads)
  {
    const int dd = tid & 63;
    const int cb = (tid >> 6) * 32;
#pragma unroll 8
    for (int c = 0; c < 32; ++c)
      wt[dd * WTSTRIDE + cb + c] = W[(cb + c) * OUT_F + dd];
  }
  __syncthreads();

  float acc[8] = {0.f, 0.f, 0.f, 0.f, 0.f, 0.f, 0.f, 0.f};
  const float* hb = hs + (quad * 8) * HSTRIDE;
  const float* wr = wt + d * WTSTRIDE;
#pragma unroll 4
  for (int c4 = 0; c4 < IN_F / 4; ++c4) {
    const float4 wv = *(const float4*)(wr + c4 * 4);
#pragma unroll
    for (int j = 0; j < 8; ++j) {
      const float4 hv = *(const float4*)(hb + j * HSTRIDE + c4 * 4);
      acc[j] = fmaf(hv.x, wv.x, acc[j]);
      acc[j] = fmaf(hv.y, wv.y, acc[j]);
      acc[j] = fmaf(hv.z, wv.z, acc[j]);
      acc[j] = fmaf(hv.w, wv.w, acc[j]);
    }
  }

  // direct whF fragment store (16B contiguous per thread)
  {
    ushortx4 lo = {bf16_bits(acc[0]), bf16_bits(acc[1]),
                   bf16_bits(acc[2]), bf16_bits(acc[3])};
    ushortx4 hi = {bf16_bits(acc[4]), bf16_bits(acc[5]),
                   bf16_bits(acc[6]), bf16_bits(acc[7])};
    unsigned short* dst = whF + ((long)c32 * 256 + w * 64 + L) * 8;
    *(ushortx4*)(dst) = lo;
    *(ushortx4*)(dst + 4) = hi;
  }

  // s1/s2: reduce acc[j]*a1[d], acc[j]*a2[d] over the 64 dims.
  const float a1d = a[d], a2d = a[OUT_F + d];
  float p1[8], p2[8];
#pragma unroll
  for (int j = 0; j < 8; ++j) { p1[j] = acc[j] * a1d; p2[j] = acc[j] * a2d; }
#pragma unroll
  for (int off = 1; off < 16; off <<= 1) {  // reduce across r16 within quad
#pragma unroll
    for (int j = 0; j < 8; ++j) {
      p1[j] += __shfl_xor(p1[j], off);
      p2[j] += __shfl_xor(p2[j], off);
    }
  }
  if (r16 == 0) {
#pragma unroll
    for (int j = 0; j < 8; ++j) {
      sred[w][quad][j][0] = p1[j];
      sred[w][quad][j][1] = p2[j];
    }
  }
  __syncthreads();
  if (tid < 32) {
    const int q = tid >> 3, j = tid & 7;
    float v1 = 0.f, v2 = 0.f;
#pragma unroll
    for (int ww = 0; ww < 4; ++ww) {
      v1 += sred[ww][q][j][0];
      v2 += sred[ww][q][j][1];
    }
    const int row = c32 * 32 + q * 8 + j;
    s1[row] = v1;
    s2[row] = v2;
  }
}

__device__ __forceinline__ void p_write(unsigned short* pr, int c, int4 av,
                                        float4 s2v, float s1w) {
  float e0 = s1w + s2v.x; e0 = fmaxf(e0, LRELU_ALPHA * e0);
  float e1 = s1w + s2v.y; e1 = fmaxf(e1, LRELU_ALPHA * e1);
  float e2 = s1w + s2v.z; e2 = fmaxf(e2, LRELU_ALPHA * e2);
  float e3 = s1w + s2v.w; e3 = fmaxf(e3, LRELU_ALPHA * e3);
  const float p0 = av.x > 0 ? __expf(e0) : 0.f;
  const float p1 = av.y > 0 ? __expf(e1) : 0.f;
  const float p2 = av.z > 0 ? __expf(e2) : 0.f;
  const float p3 = av.w > 0 ? __expf(e3) : 0.f;
  ushortx4 pk = {bf16_bits(p0), bf16_bits(p1), bf16_bits(p2), bf16_bits(p3)};
  *(ushortx4*)(pr + c) = pk;
}

// Fused GAT v2.1: 512 blocks x 512 thr (8 waves), 16 rows/block.
// Wave w owns adj rows {2w, 2w+1} (contiguous 1KB bursts) and MFMA col-chunks
// {w, w+8}. adj prefetched TWO iters ahead; refill loads interleaved with the
// p_writes that consume each register set, so they get VALU shadow before the
// barrier's implicit vmcnt(0) drain. 512-thr blocks => 2 blocks/CU.
__global__ __launch_bounds__(512, 4) void gat_kernel(
    const int* __restrict__ adj, const float* __restrict__ s1,
    const float* __restrict__ s2, const unsigned short* __restrict__ whF,
    float* __restrict__ out) {
  __shared__ __align__(16) unsigned short pbuf[2][16][PAD];  // 33280 B
  const int tid = threadIdx.x;
  const int w = tid >> 6, L = tid & 63;
  const int r16 = L & 15, quad = L >> 4;
  const int row0 = blockIdx.x * 16;
  const int rA = 2 * w, rB = 2 * w + 1;
  const long arowA = (long)(row0 + rA) * N;
  const long arowB = (long)(row0 + rB) * N;
  const float s1A = s1[row0 + rA];
  const float s1B = s1[row0 + rB];
  const int c = L * 4;

  float4v acc0 = {0.f, 0.f, 0.f, 0.f};
  float4v acc1 = {0.f, 0.f, 0.f, 0.f};
  float4v acc2 = {0.f, 0.f, 0.f, 0.f};
  float4v acc3 = {0.f, 0.f, 0.f, 0.f};
  float4v accD = {0.f, 0.f, 0.f, 0.f};
  const short ONE = (short)0x3F80;  // bf16 1.0
  const short8 ones = {ONE, ONE, ONE, ONE, ONE, ONE, ONE, ONE};

  // 2-deep adj prefetch regs: set s holds segment (it+1) where s == it&1
  int4 pA0[2], pA1[2], pB0[2], pB1[2];
  float4 ps0, ps1;  // s2, 1-deep (L2-hot)

  // prologue: seg0 p + issue prefetches for seg1/seg2
  {
    const int4 a0 = *(const int4*)(adj + arowA + c);
    const int4 a1 = *(const int4*)(adj + arowA + 256 + c);
    const int4 b0 = *(const int4*)(adj + arowB + c);
    const int4 b1 = *(const int4*)(adj + arowB + 256 + c);
    const float4 sv0 = *(const float4*)(s2 + c);
    const float4 sv1 = *(const float4*)(s2 + 256 + c);
    pA0[0] = *(const int4*)(adj + arowA + 512 + c);
    pA1[0] = *(const int4*)(adj + arowA + 512 + 256 + c);
    pB0[0] = *(const int4*)(adj + arowB + 512 + c);
    pB1[0] = *(const int4*)(adj + arowB + 512 + 256 + c);
    pA0[1] = *(const int4*)(adj + arowA + 1024 + c);
    pA1[1] = *(const int4*)(adj + arowA + 1024 + 256 + c);
    pB0[1] = *(const int4*)(adj + arowB + 1024 + c);
    pB1[1] = *(const int4*)(adj + arowB + 1024 + 256 + c);
    ps0 = *(const float4*)(s2 + 512 + c);
    ps1 = *(const float4*)(s2 + 512 + 256 + c);
    p_write(pbuf[0][rA], c, a0, sv0, s1A);
    p_write(pbuf[0][rA], 256 + c, a1, sv1, s1A);
    p_write(pbuf[0][rB], c, b0, sv0, s1B);
    p_write(pbuf[0][rB], 256 + c, b1, sv1, s1B);
  }
  __syncthreads();

#pragma unroll
  for (int it = 0; it < 16; ++it) {
    const int b = it & 1;
    const int s = it & 1;
    // MFMA phase: this wave's two 32-col chunks (accumulate over cols)
#pragma unroll
    for (int half = 0; half < 2; ++half) {
      const int cc = w + half * 8;
      const short8 afrag = *(const short8*)(&pbuf[b][r16][cc * 32 + quad * 8]);
      const unsigned short* bp = whF + ((long)(it * 16 + cc) * 256 + L) * 8;
      const short8 b0 = *(const short8*)(bp);
      const short8 b1 = *(const short8*)(bp + 512);
      const short8 b2 = *(const short8*)(bp + 1024);
      const short8 b3 = *(const short8*)(bp + 1536);
      acc0 = __builtin_amdgcn_mfma_f32_16x16x32_bf16(afrag, b0, acc0, 0, 0, 0);
      acc1 = __builtin_amdgcn_mfma_f32_16x16x32_bf16(afrag, b1, acc1, 0, 0, 0);
      acc2 = __builtin_amdgcn_mfma_f32_16x16x32_bf16(afrag, b2, acc2, 0, 0, 0);
      acc3 = __builtin_amdgcn_mfma_f32_16x16x32_bf16(afrag, b3, acc3, 0, 0, 0);
      accD = __builtin_amdgcn_mfma_f32_16x16x32_bf16(afrag, ones, accD, 0, 0, 0);
    }
    if (it < 15) {  // stage p(it+1); refill each reg set right after consume
      unsigned short* prA = pbuf[b ^ 1][rA];
      unsigned short* prB = pbuf[b ^ 1][rB];
      const long base = (long)(it + 3) * 512 + c;
      p_write(prA, c, pA0[s], ps0, s1A);
      if (it < 13) pA0[s] = *(const int4*)(adj + arowA + base);
      p_write(prA, 256 + c, pA1[s], ps1, s1A);
      if (it < 13) pA1[s] = *(const int4*)(adj + arowA + base + 256);
      p_write(prB, c, pB0[s], ps0, s1B);
      if (it < 13) pB0[s] = *(const int4*)(adj + arowB + base);
      p_write(prB, 256 + c, pB1[s], ps1, s1B);
      if (it < 13) pB1[s] = *(const int4*)(adj + arowB + base + 256);
      if (it < 14) {  // s2 for segment it+2
        ps0 = *(const float4*)(s2 + (it + 2) * 512 + c);
        ps1 = *(const float4*)(s2 + (it + 2) * 512 + 256 + c);
      }
    }
    __syncthreads();
  }

  // merge 8 wave-partials in LDS (aliases pbuf; 4 slots x 1040 floats)
  float* M = (float*)pbuf;
  if (w >= 4) {
    float* S = M + (w - 4) * 1040;
#pragma unroll
    for (int reg = 0; reg < 4; ++reg) {
      const int r = quad * 4 + reg;  // C-layout: row=quad*4+reg, col=r16
      S[r * 64 + 0 * 16 + r16] = acc0[reg];
      S[r * 64 + 1 * 16 + r16] = acc1[reg];
      S[r * 64 + 2 * 16 + r16] = acc2[reg];
      S[r * 64 + 3 * 16 + r16] = acc3[reg];
      if (r16 == 0) S[1024 + r] = accD[reg];
    }
  }
  __syncthreads();
  if (w < 4) {
    float* S = M + w * 1040;
#pragma unroll
    for (int reg = 0; reg < 4; ++reg) {
      const int r = quad * 4 + reg;
      S[r * 64 + 0 * 16 + r16] += acc0[reg];
      S[r * 64 + 1 * 16 + r16] += acc1[reg];
      S[r * 64 + 2 * 16 + r16] += acc2[reg];
      S[r * 64 + 3 * 16 + r16] += acc3[reg];
      if (r16 == 0) S[1024 + r] += accD[reg];
    }
  }
  __syncthreads();
#pragma unroll
  for (int part = 0; part < 2; ++part) {
    const int e = part * 512 + tid;
    const int r = e >> 6, k = e & 63;
    float Sv = 0.f, Lv = 0.f;
#pragma unroll
    for (int sl = 0; sl < 4; ++sl) {
      Sv += M[sl * 1040 + r * 64 + k];
      Lv += M[sl * 1040 + 1024 + r];
    }
    const float v = Sv / Lv;
    out[(long)(row0 + r) * OUT_F + k] = v > 0.f ? v : expm1f(v);
  }
}

extern "C" void kernel_launch(void* const* d_in, const int* in_sizes, int n_in,
                              void* d_out, int out_size, void* d_ws, size_t ws_size,
                              hipStream_t stream) {
  const float* h = (const float*)d_in[0];
  const int* adj = (const int*)d_in[1];
  const float* W = (const float*)d_in[2];
  const float* a = (const float*)d_in[3];
  float* out = (float*)d_out;

  // ws: s1[8192] | s2[8192] | whF[64*8192] bf16 (~1.1MB)
  float* s1 = (float*)d_ws;
  float* s2 = s1 + N;
  unsigned short* whF = (unsigned short*)(s2 + N);

  prep_kernel<<<N / 32, 256, 0, stream>>>(h, W, a, s1, s2, whF);
  gat_kernel<<<N / 16, 512, 0, stream>>>(adj, s1, s2, whF, out);
}